// Round 4
// baseline (1394.803 us; speedup 1.0000x reference)
//
#include <hip/hip_runtime.h>
#include <hip/hip_bf16.h>
#include <cmath>

#define T_TOK 8192
#define E_NUM 8
#define D_DIM 1024
#define H_DIM 4096

typedef __attribute__((ext_vector_type(4))) short bf16x4;
typedef __attribute__((ext_vector_type(8))) short bf16x8;
typedef __attribute__((ext_vector_type(4))) float f32x4;

__device__ __forceinline__ unsigned short f2bf(float f) {
  union { float f; unsigned u; } v; v.f = f;
  unsigned r = v.u + 0x7fffu + ((v.u >> 16) & 1u);
  return (unsigned short)(r >> 16);
}

__device__ __forceinline__ void gload_lds16(const void* g, void* l) {
  __builtin_amdgcn_global_load_lds(
      (const __attribute__((address_space(1))) unsigned int*)g,
      (__attribute__((address_space(3))) unsigned int*)l, 16, 0, 0);
}

// k-permutation within each 32-element group: element k stored at pos
// c*8 + h*4 + r  (c=(k>>2)&3, h=(k>>4)&1, r=k&3).  Lane-quarter q then reads
// its MFMA fragment (k in [4q,4q+4) u [16+4q,16+4q+4)) as ONE contiguous b128,
// with register j-order (k = 16*(j>>2) + 4q + (j&3)) matching automatically.

// ---------------- convert x: fp32 -> bf16, k-permuted ----------------
__global__ void __launch_bounds__(256) cvt_x_kernel(const float* __restrict__ x,
                                                    ushort* __restrict__ xb) {
  int i = blockIdx.x * 256 + threadIdx.x;  // 4-group index; c,h constant in group
  float4 v = ((const float4*)x)[i];
  ushort4 o;
  o.x = f2bf(v.x); o.y = f2bf(v.y); o.z = f2bf(v.z); o.w = f2bf(v.w);
  int u = i & 7;                                  // 4-group within 32-group
  int oi = (i & ~7) | (((u & 3) << 1) | (u >> 2)); // pos4 = c*2 + h
  ((ushort4*)xb)[oi] = o;
}

// ---- transpose + convert weights: [K][N] fp32 -> [N][K-permuted] bf16 ----
// 64x64 tile, 256 threads: float4 reads, ushort8 pos-ordered writes.
__global__ void __launch_bounds__(256) transpose_cvt_kernel(
    const float* __restrict__ src, ushort* __restrict__ dst, int K, int N) {
  __shared__ __align__(16) float tile[64][68];
  size_t eoff = (size_t)blockIdx.z * K * N;
  int n0 = blockIdx.x * 64, k0 = blockIdx.y * 64;
  int t = threadIdx.x;
  int kr = t >> 4, nc = (t & 15) * 4;
#pragma unroll
  for (int i = 0; i < 4; ++i) {
    float4 v = *(const float4*)(src + eoff + (size_t)(k0 + kr + i * 16) * N + n0 + nc);
    *(float4*)&tile[kr + i * 16][nc] = v;
  }
  __syncthreads();
  int n = t >> 3, s = t & 7, g = s >> 2, p = s & 3;  // 16B slot (g,p): c=p
#pragma unroll
  for (int j = 0; j < 2; ++j) {
    int nn = n + j * 32;
    union { bf16x8 v8; ushort e[8]; } o;
#pragma unroll
    for (int h = 0; h < 2; ++h)
#pragma unroll
      for (int r = 0; r < 4; ++r) {
        int k = g * 32 + h * 16 + p * 4 + r;
        o.e[h * 4 + r] = f2bf(tile[k][nn]);
      }
    *(bf16x8*)(dst + eoff + (size_t)(n0 + nn) * K + k0 + g * 32 + p * 8) = o.v8;
  }
}

// ---------------- router: fp32, one wave per token ----------------
__global__ void __launch_bounds__(256) router_kernel(
    const float* __restrict__ x, const float* __restrict__ eps,
    const float* __restrict__ Wg, const float* __restrict__ bg,
    const float* __restrict__ Wn, const float* __restrict__ bn,
    int* __restrict__ tok, float* __restrict__ gateL, int* __restrict__ cnt) {
  int lane = threadIdx.x & 63;
  int t = blockIdx.x * 4 + (threadIdx.x >> 6);
  float ag[8], an[8];
#pragma unroll
  for (int e = 0; e < 8; ++e) { ag[e] = 0.f; an[e] = 0.f; }
  const float* xr = x + (size_t)t * D_DIM;
#pragma unroll 4
  for (int i = 0; i < 16; ++i) {
    int d = lane + i * 64;
    float xv = xr[d];
    const float4* g4 = (const float4*)(Wg + d * 8);
    const float4* n4 = (const float4*)(Wn + d * 8);
    float4 ga = g4[0], gb = g4[1], na = n4[0], nb = n4[1];
    ag[0] += xv * ga.x; ag[1] += xv * ga.y; ag[2] += xv * ga.z; ag[3] += xv * ga.w;
    ag[4] += xv * gb.x; ag[5] += xv * gb.y; ag[6] += xv * gb.z; ag[7] += xv * gb.w;
    an[0] += xv * na.x; an[1] += xv * na.y; an[2] += xv * na.z; an[3] += xv * na.w;
    an[4] += xv * nb.x; an[5] += xv * nb.y; an[6] += xv * nb.z; an[7] += xv * nb.w;
  }
#pragma unroll
  for (int off = 32; off > 0; off >>= 1) {
#pragma unroll
    for (int e = 0; e < 8; ++e) {
      ag[e] += __shfl_xor(ag[e], off);
      an[e] += __shfl_xor(an[e], off);
    }
  }
  if (lane == 0) {
    float noisy[8];
#pragma unroll
    for (int e = 0; e < 8; ++e) {
      float lg = ag[e] + bg[e];
      float ln = an[e] + bn[e];
      float sp = (ln > 20.f) ? ln : log1pf(expf(ln));
      noisy[e] = lg + eps[(size_t)t * 8 + e] * sp;
    }
    int i0 = 0; float v0 = noisy[0];
#pragma unroll
    for (int e = 1; e < 8; ++e) if (noisy[e] > v0) { v0 = noisy[e]; i0 = e; }
    int i1 = -1; float v1 = -1e30f;
#pragma unroll
    for (int e = 0; e < 8; ++e) if (e != i0 && noisy[e] > v1) { v1 = noisy[e]; i1 = e; }
    float ee = expf(v1 - v0);
    float g0 = 1.f / (1.f + ee);
    float g1 = ee / (1.f + ee);
    int p0 = atomicAdd(cnt + i0, 1);
    int p1 = atomicAdd(cnt + i1, 1);
    tok[i0 * T_TOK + p0] = t * 2;     gateL[i0 * T_TOK + p0] = g0;
    tok[i1 * T_TOK + p1] = t * 2 + 1; gateL[i1 * T_TOK + p1] = g1;
  }
}

// -------- gathered GEMM, 2-phase double-buffered (T3-minimum), 128x128 --------
// BK=64, 4 waves; stage NEXT K-tile via global_load_lds(16B) BEFORE computing
// current buffer; single __syncthreads per K-tile (its implicit vmcnt/lgkmcnt
// drain completes loads that overlapped the whole compute phase).
// Operands k-permuted (b128 fragments) + 16B-slot XOR swizzle on the global
// source with matching XOR on ds_read (rule #21) -> 0 bank conflicts.
template <int KD, int NC, bool FIRST>
__global__ void __launch_bounds__(256, 2) moe_gemm_kernel(
    const ushort* __restrict__ Abase, const ushort* __restrict__ Bt,
    const float* __restrict__ bias, const int* __restrict__ tok,
    const float* __restrict__ gateL, const int* __restrict__ cnt,
    ushort* __restrict__ hbuf, float* __restrict__ out) {
  constexpr int MT = T_TOK / 128;
  constexpr int NT = NC / 128;
  constexpr int NKT = KD / 64;
  int nwg = MT * NT * E_NUM;
  int q8 = nwg >> 3;
  int bid = blockIdx.x;
  int wg = (bid & 7) * q8 + (bid >> 3);   // bijective XCD chunking (nwg%8==0)
  int m_t = wg % MT;
  int n_t = (wg / MT) % NT;
  int e = wg / (MT * NT);

  int c = cnt[e];
  int m0 = m_t * 128;
  if (m0 >= c) return;
  int n0 = n_t * 128;

  __shared__ __align__(16) ushort As[2][128 * 64];  // 2 x 16 KB
  __shared__ __align__(16) ushort Bs[2][128 * 64];  // total LDS = 64 KB
  int tid = threadIdx.x;
  int lane = tid & 63, wave = tid >> 6;
  int wr = (wave >> 1) * 64, wc = (wave & 1) * 64;
  const int* tokE = tok + e * T_TOK;
  const ushort* Be = Bt + (size_t)e * NC * KD;

  int srow = tid >> 3, scol = tid & 7;
  const ushort* asrc[4]; const ushort* bsrc[4];
#pragma unroll
  for (int p = 0; p < 4; ++p) {
    int r = p * 32 + srow;
    int pi = m0 + r;
    int ar = 0;
    if (pi < c) { int tsv = tokE[pi]; ar = FIRST ? (tsv >> 1) : tsv; }
    int sl = (scol ^ (r & 7)) * 8;  // pre-swizzled global 16B slot
    asrc[p] = Abase + (size_t)ar * KD + sl;
    bsrc[p] = Be + (size_t)(n0 + r) * KD + sl;
  }

  f32x4 acc[4][4];
#pragma unroll
  for (int i = 0; i < 4; ++i)
#pragma unroll
    for (int j = 0; j < 4; ++j) {
      f32x4 z = {0.f, 0.f, 0.f, 0.f};
      acc[i][j] = z;
    }

  int r16 = lane & 15;
  int q = lane >> 4;
  int rr = lane & 7;
  int s0 = (q ^ rr) << 4;   // swizzled byte-in-row of this lane's ks=0 slot

  // prologue: stage tile 0 into buffer 0
#pragma unroll
  for (int p = 0; p < 4; ++p) {
    gload_lds16(asrc[p], (char*)As[0] + p * 4096 + tid * 16);
    gload_lds16(bsrc[p], (char*)Bs[0] + p * 4096 + tid * 16);
  }
  __syncthreads();  // drains vmcnt(0): tile 0 resident

  int cur = 0;
  for (int kt = 0; kt < NKT; ++kt) {
    // phase A: issue next tile's stage into the other buffer (overlaps compute)
    if (kt + 1 < NKT) {
#pragma unroll
      for (int p = 0; p < 4; ++p) {
        gload_lds16(asrc[p] + (kt + 1) * 64, (char*)As[cur ^ 1] + p * 4096 + tid * 16);
        gload_lds16(bsrc[p] + (kt + 1) * 64, (char*)Bs[cur ^ 1] + p * 4096 + tid * 16);
      }
    }
    // phase B: compute current buffer
    const char* Ab = (const char*)As[cur];
    const char* Bb = (const char*)Bs[cur];
#pragma unroll
    for (int ks = 0; ks < 2; ++ks) {
      const int so = s0 ^ (ks << 6);
      bf16x8 af[4], bfr[4];
#pragma unroll
      for (int i = 0; i < 4; ++i) {
        af[i]  = *(const bf16x8*)(Ab + (wr + i * 16 + r16) * 128 + so);
        bfr[i] = *(const bf16x8*)(Bb + (wc + i * 16 + r16) * 128 + so);
      }
#pragma unroll
      for (int mi = 0; mi < 4; ++mi)
#pragma unroll
        for (int ni = 0; ni < 4; ++ni)
          acc[mi][ni] = __builtin_amdgcn_mfma_f32_16x16x32_bf16(
              af[mi], bfr[ni], acc[mi][ni], 0, 0, 0);
    }
    __syncthreads();  // drain: next tile landed; all reads of cur done
    cur ^= 1;
  }

  const float* be = bias + (size_t)e * NC;
#pragma unroll
  for (int mi = 0; mi < 4; ++mi) {
#pragma unroll
    for (int r = 0; r < 4; ++r) {
      int rowl = wr + mi * 16 + q * 4 + r;
      int p = m0 + rowl;
      if (p < c) {
        int tsv = tokE[p];
        if (FIRST) {
          ushort* hrow = hbuf + (size_t)tsv * H_DIM;
#pragma unroll
          for (int ni = 0; ni < 4; ++ni) {
            int col = n0 + wc + ni * 16 + r16;
            float v = acc[mi][ni][r] + be[col];
            v = 0.5f * v * (1.f + erff(v * 0.70710678118654752f));
            // store k-permuted so hbuf rows feed GEMM2 directly
            int pos = ((r16 >> 2) & 3) * 8 + (ni & 1) * 4 + (r16 & 3);
            hrow[(col & ~31) + pos] = f2bf(v);
          }
        } else {
          float g = gateL[e * T_TOK + p];
          float* orow = out + (size_t)(tsv >> 1) * D_DIM;
#pragma unroll
          for (int ni = 0; ni < 4; ++ni) {
            int col = n0 + wc + ni * 16 + r16;
            float v = acc[mi][ni][r] + be[col];
            atomicAdd(&orow[col], g * v);
          }
        }
      }
    }
  }
}

extern "C" void kernel_launch(void* const* d_in, const int* in_sizes, int n_in,
                              void* d_out, int out_size, void* d_ws, size_t ws_size,
                              hipStream_t stream) {
  const float* x   = (const float*)d_in[0];
  const float* eps = (const float*)d_in[1];
  const float* Wg  = (const float*)d_in[2];
  const float* bg  = (const float*)d_in[3];
  const float* Wn  = (const float*)d_in[4];
  const float* bn  = (const float*)d_in[5];
  const float* W1  = (const float*)d_in[6];
  const float* b1  = (const float*)d_in[7];
  const float* W2  = (const float*)d_in[8];
  const float* b2  = (const float*)d_in[9];
  float* out = (float*)d_out;

  const size_t nXB = (size_t)T_TOK * D_DIM;
  const size_t nW1 = (size_t)E_NUM * D_DIM * H_DIM;
  const size_t nHB = (size_t)T_TOK * 2 * H_DIM;
  ushort* xb   = (ushort*)d_ws;
  ushort* W1T  = xb + nXB;            // [E][H][D-perm] bf16
  ushort* W2T  = W1T + nW1;           // [E][D][H-perm] bf16
  ushort* hbuf = W2T + nW1;           // [T*2][H-perm] bf16
  int*   tok   = (int*)(hbuf + nHB);  // [E][T] token*2+slot
  float* gateL = (float*)(tok + E_NUM * T_TOK);
  int*   cnt   = (int*)(gateL + E_NUM * T_TOK);
  size_t need = (size_t)((char*)(cnt + 8) - (char*)d_ws);
  if (ws_size < need) return;

  hipMemsetAsync(cnt, 0, 8 * sizeof(int), stream);
  hipMemsetAsync(out, 0, (size_t)out_size * sizeof(float), stream);

  cvt_x_kernel<<<(int)(nXB / 4 / 256), 256, 0, stream>>>(x, xb);
  transpose_cvt_kernel<<<dim3(H_DIM / 64, D_DIM / 64, E_NUM), 256, 0, stream>>>(
      W1, W1T, D_DIM, H_DIM);
  transpose_cvt_kernel<<<dim3(D_DIM / 64, H_DIM / 64, E_NUM), 256, 0, stream>>>(
      W2, W2T, H_DIM, D_DIM);
  router_kernel<<<T_TOK / 4, 256, 0, stream>>>(x, eps, Wg, bg, Wn, bn, tok, gateL, cnt);
  moe_gemm_kernel<D_DIM, H_DIM, true>
      <<<(T_TOK / 128) * (H_DIM / 128) * E_NUM, 256, 0, stream>>>(
          xb, W1T, b1, tok, gateL, cnt, hbuf, out);
  moe_gemm_kernel<H_DIM, D_DIM, false>
      <<<(T_TOK / 128) * (D_DIM / 128) * E_NUM, 256, 0, stream>>>(
          hbuf, W2T, b2, tok, gateL, cnt, hbuf, out);
}

// Round 6
// 1258.716 us; speedup vs baseline: 1.1081x; 1.1081x over previous
//
#include <hip/hip_runtime.h>
#include <hip/hip_bf16.h>
#include <cmath>

#define T_TOK 8192
#define E_NUM 8
#define D_DIM 1024
#define H_DIM 4096
#define GROWS 18432  // padded compact row space: 16384 + 8*256 max

typedef __attribute__((ext_vector_type(4))) short bf16x4;
typedef __attribute__((ext_vector_type(8))) short bf16x8;
typedef __attribute__((ext_vector_type(4))) float f32x4;

__device__ __forceinline__ unsigned short f2bf(float f) {
  union { float f; unsigned u; } v; v.f = f;
  unsigned r = v.u + 0x7fffu + ((v.u >> 16) & 1u);
  return (unsigned short)(r >> 16);
}

__device__ __forceinline__ void gload_lds16(const void* g, void* l) {
  __builtin_amdgcn_global_load_lds(
      (const __attribute__((address_space(1))) unsigned int*)g,
      (__attribute__((address_space(3))) unsigned int*)l, 16, 0, 0);
}

// k-permutation within each 32-element K-group: element k stored at pos
// c*8 + h*4 + r  (c=(k>>2)&3, h=(k>>4)&1, r=k&3).  Lane-quarter q reads its
// 16x16x32 fragment as ONE b128 with register order matching automatically.

// ---- transpose + convert weights: [K][N] fp32 -> [N][K-permuted] bf16 ----
__global__ void __launch_bounds__(256) transpose_cvt_kernel(
    const float* __restrict__ src, ushort* __restrict__ dst, int K, int N) {
  __shared__ __align__(16) float tile[64][68];
  size_t eoff = (size_t)blockIdx.z * K * N;
  int n0 = blockIdx.x * 64, k0 = blockIdx.y * 64;
  int t = threadIdx.x;
  int kr = t >> 4, nc = (t & 15) * 4;
#pragma unroll
  for (int i = 0; i < 4; ++i) {
    float4 v = *(const float4*)(src + eoff + (size_t)(k0 + kr + i * 16) * N + n0 + nc);
    *(float4*)&tile[kr + i * 16][nc] = v;
  }
  __syncthreads();
  int n = t >> 3, s = t & 7, g = s >> 2, p = s & 3;
#pragma unroll
  for (int j = 0; j < 2; ++j) {
    int nn = n + j * 32;
    union { bf16x8 v8; ushort e[8]; } o;
#pragma unroll
    for (int h = 0; h < 2; ++h)
#pragma unroll
      for (int r = 0; r < 4; ++r) {
        int k = g * 32 + h * 16 + p * 4 + r;
        o.e[h * 4 + r] = f2bf(tile[k][nn]);
      }
    *(bf16x8*)(dst + eoff + (size_t)(n0 + nn) * K + k0 + g * 32 + p * 8) = o.v8;
  }
}

// ---------------- router: fp32, one wave per token ----------------
__global__ void __launch_bounds__(256) router_kernel(
    const float* __restrict__ x, const float* __restrict__ eps,
    const float* __restrict__ Wg, const float* __restrict__ bg,
    const float* __restrict__ Wn, const float* __restrict__ bn,
    int* __restrict__ tok, float* __restrict__ gateL, int* __restrict__ cnt) {
  int lane = threadIdx.x & 63;
  int t = blockIdx.x * 4 + (threadIdx.x >> 6);
  float ag[8], an[8];
#pragma unroll
  for (int e = 0; e < 8; ++e) { ag[e] = 0.f; an[e] = 0.f; }
  const float* xr = x + (size_t)t * D_DIM;
#pragma unroll 4
  for (int i = 0; i < 16; ++i) {
    int d = lane + i * 64;
    float xv = xr[d];
    const float4* g4 = (const float4*)(Wg + d * 8);
    const float4* n4 = (const float4*)(Wn + d * 8);
    float4 ga = g4[0], gb = g4[1], na = n4[0], nb = n4[1];
    ag[0] += xv * ga.x; ag[1] += xv * ga.y; ag[2] += xv * ga.z; ag[3] += xv * ga.w;
    ag[4] += xv * gb.x; ag[5] += xv * gb.y; ag[6] += xv * gb.z; ag[7] += xv * gb.w;
    an[0] += xv * na.x; an[1] += xv * na.y; an[2] += xv * na.z; an[3] += xv * na.w;
    an[4] += xv * nb.x; an[5] += xv * nb.y; an[6] += xv * nb.z; an[7] += xv * nb.w;
  }
#pragma unroll
  for (int off = 32; off > 0; off >>= 1) {
#pragma unroll
    for (int e = 0; e < 8; ++e) {
      ag[e] += __shfl_xor(ag[e], off);
      an[e] += __shfl_xor(an[e], off);
    }
  }
  if (lane == 0) {
    float noisy[8];
#pragma unroll
    for (int e = 0; e < 8; ++e) {
      float lg = ag[e] + bg[e];
      float ln = an[e] + bn[e];
      float sp = (ln > 20.f) ? ln : log1pf(expf(ln));
      noisy[e] = lg + eps[(size_t)t * 8 + e] * sp;
    }
    int i0 = 0; float v0 = noisy[0];
#pragma unroll
    for (int e = 1; e < 8; ++e) if (noisy[e] > v0) { v0 = noisy[e]; i0 = e; }
    int i1 = -1; float v1 = -1e30f;
#pragma unroll
    for (int e = 0; e < 8; ++e) if (e != i0 && noisy[e] > v1) { v1 = noisy[e]; i1 = e; }
    float ee = expf(v1 - v0);
    float g0 = 1.f / (1.f + ee);
    float g1 = ee / (1.f + ee);
    int p0 = atomicAdd(cnt + i0, 1);
    int p1 = atomicAdd(cnt + i1, 1);
    tok[i0 * T_TOK + p0] = t * 2;     gateL[i0 * T_TOK + p0] = g0;
    tok[i1 * T_TOK + p1] = t * 2 + 1; gateL[i1 * T_TOK + p1] = g1;
  }
}

// ---------------- plan: 256-aligned per-expert compact offsets ----------------
__global__ void plan_kernel(const int* __restrict__ cnt, int* __restrict__ goff) {
  if (threadIdx.x == 0) {
    int a = 0; goff[0] = 0;
#pragma unroll
    for (int e = 0; e < 8; ++e) { a += (cnt[e] + 255) & ~255; goff[e + 1] = a; }
  }
}

// -------- compact: gather+convert+k-perm x rows into contiguous xg --------
__global__ void __launch_bounds__(256) compact_kernel(
    const float* __restrict__ x, const int* __restrict__ tok,
    const float* __restrict__ gateL, const int* __restrict__ cnt,
    const int* __restrict__ goff, ushort* __restrict__ xg,
    float* __restrict__ gateg, int* __restrict__ rowg) {
  int idx = blockIdx.x * 256 + threadIdx.x;   // GROWS*128 threads total
  int g = idx >> 7, ch = idx & 127;           // ch = 16B out chunk (8 bf16)
  int e = 0;
  while (g >= goff[e + 1]) ++e;
  int p = g - goff[e];
  ushort* dst = xg + (size_t)g * D_DIM + ch * 8;
  if (p < cnt[e]) {
    int tsv = tok[e * T_TOK + p];
    int trow = tsv >> 1;
    int gb = ch >> 2, s = ch & 3;  // 32-group, slot
    const float* src = x + (size_t)trow * D_DIM + gb * 32;
    float4 lo = *(const float4*)(src + s * 4);       // k = s*4 + r
    float4 hi = *(const float4*)(src + 16 + s * 4);  // k = 16 + s*4 + r
    union { bf16x8 v; ushort u[8]; } o;
    o.u[0] = f2bf(lo.x); o.u[1] = f2bf(lo.y); o.u[2] = f2bf(lo.z); o.u[3] = f2bf(lo.w);
    o.u[4] = f2bf(hi.x); o.u[5] = f2bf(hi.y); o.u[6] = f2bf(hi.z); o.u[7] = f2bf(hi.w);
    *(bf16x8*)dst = o.v;
    if (ch == 0) { gateg[g] = gateL[e * T_TOK + p]; rowg[g] = trow; }
  } else {
    bf16x8 z = {0, 0, 0, 0, 0, 0, 0, 0};
    *(bf16x8*)dst = z;
  }
}

// ---- 2-phase dbuf GEMM, 256xBN tile, BK=64, 8 waves (2M x 4N), contiguous A ----
// FIRST=true : hbuf[g] = gelu(xg[g]@W1[e]+b1[e]) k-permuted  (BN=256)
// FIRST=false: out[rowg[g]] += gateg[g]*(hbuf[g]@W2[e]+b2[e]) (BN=128, atomic)
template <int KD, int NC, int BN, bool FIRST>
__global__ void __launch_bounds__(512, 2) moe_gemm_kernel(
    const ushort* __restrict__ Abase, const ushort* __restrict__ Bt,
    const float* __restrict__ bias, const int* __restrict__ goff,
    const int* __restrict__ cnt, const float* __restrict__ gateg,
    const int* __restrict__ rowg, ushort* __restrict__ hbuf,
    float* __restrict__ out) {
  constexpr int NMT = GROWS / 256;     // 72
  constexpr int NT = NC / BN;
  constexpr int NKT = KD / 64;
  constexpr int NFRAG = BN / 64;       // 4 (GEMM1) or 2 (GEMM2)
  constexpr int WN = BN / 4;
  constexpr int APL = 4;               // 256*8 slots / 512 threads
  constexpr int BPL = BN * 8 / 512;

  int nwg = NMT * NT;
  int q8 = nwg >> 3;
  int bid = blockIdx.x;
  int wg = (bid & 7) * q8 + (bid >> 3);  // bijective XCD chunking (nwg%8==0)
  int mt = wg % NMT;                      // m fastest: B-panel L2 reuse per XCD
  int n_t = wg / NMT;

  int m0g = mt * 256;
  if (m0g >= goff[8]) return;
  int e = 0;
  while (m0g >= goff[e + 1]) ++e;
  int glim = goff[e] + cnt[e];
  int n0 = n_t * BN;

  __shared__ __align__(16) ushort As[2][256 * 64];
  __shared__ __align__(16) ushort Bs[2][BN * 64];

  int tid = threadIdx.x;
  int lane = tid & 63, wave = tid >> 6;
  int wm = wave >> 2, wn = wave & 3;

  const ushort* asrc[APL];
#pragma unroll
  for (int p = 0; p < APL; ++p) {
    int sidx = p * 512 + tid;
    int row = sidx >> 3, sc = sidx & 7;
    asrc[p] = Abase + (size_t)(m0g + row) * KD + (sc ^ (row & 7)) * 8;
  }
  const ushort* bsrc[BPL];
  const ushort* Be = Bt + (size_t)e * NC * KD;
#pragma unroll
  for (int p = 0; p < BPL; ++p) {
    int sidx = p * 512 + tid;
    int row = sidx >> 3, sc = sidx & 7;
    bsrc[p] = Be + (size_t)(n0 + row) * KD + (sc ^ (row & 7)) * 8;
  }

  f32x4 acc[8][NFRAG];
#pragma unroll
  for (int i = 0; i < 8; ++i)
#pragma unroll
    for (int j = 0; j < NFRAG; ++j) {
      f32x4 z = {0.f, 0.f, 0.f, 0.f};
      acc[i][j] = z;
    }

  int r16 = lane & 15;
  int q = lane >> 4;
  int rr = lane & 7;
  int s0 = (q ^ rr) << 4;

  // prologue: stage tile 0 into buffer 0
#pragma unroll
  for (int p = 0; p < APL; ++p)
    gload_lds16(asrc[p], (char*)As[0] + (p * 512 + tid) * 16);
#pragma unroll
  for (int p = 0; p < BPL; ++p)
    gload_lds16(bsrc[p], (char*)Bs[0] + (p * 512 + tid) * 16);
  __syncthreads();

  int cur = 0;
  for (int kt = 0; kt < NKT; ++kt) {
    if (kt + 1 < NKT) {  // issue next tile's stage (overlaps compute below)
#pragma unroll
      for (int p = 0; p < APL; ++p)
        gload_lds16(asrc[p] + (kt + 1) * 64, (char*)As[cur ^ 1] + (p * 512 + tid) * 16);
#pragma unroll
      for (int p = 0; p < BPL; ++p)
        gload_lds16(bsrc[p] + (kt + 1) * 64, (char*)Bs[cur ^ 1] + (p * 512 + tid) * 16);
    }
    const char* Ab = (const char*)As[cur];
    const char* Bb = (const char*)Bs[cur];
#pragma unroll
    for (int ks = 0; ks < 2; ++ks) {
      const int so = s0 ^ (ks << 6);
      bf16x8 af[8], bf[NFRAG];
#pragma unroll
      for (int i = 0; i < 8; ++i)
        af[i] = *(const bf16x8*)(Ab + (wm * 128 + i * 16 + r16) * 128 + so);
#pragma unroll
      for (int j = 0; j < NFRAG; ++j)
        bf[j] = *(const bf16x8*)(Bb + (wn * WN + j * 16 + r16) * 128 + so);
#pragma unroll
      for (int mi = 0; mi < 8; ++mi)
#pragma unroll
        for (int nj = 0; nj < NFRAG; ++nj)
          acc[mi][nj] = __builtin_amdgcn_mfma_f32_16x16x32_bf16(
              af[mi], bf[nj], acc[mi][nj], 0, 0, 0);
    }
    __syncthreads();  // drains vmcnt: next tile resident; reads of cur done
    cur ^= 1;
  }

  const float* be = bias + (size_t)e * NC;
#pragma unroll
  for (int mi = 0; mi < 8; ++mi) {
#pragma unroll
    for (int r = 0; r < 4; ++r) {
      int grow = m0g + wm * 128 + mi * 16 + q * 4 + r;
      if (grow < glim) {
        if (FIRST) {
          ushort* hrow = hbuf + (size_t)grow * H_DIM;
#pragma unroll
          for (int nj = 0; nj < NFRAG; ++nj) {
            int col = n0 + wn * WN + nj * 16 + r16;
            float v = acc[mi][nj][r] + be[col];
            v = 0.5f * v * (1.f + erff(v * 0.70710678118654752f));
            int pos = ((r16 >> 2) & 3) * 8 + (nj & 1) * 4 + (r16 & 3);
            hrow[(col & ~31) + pos] = f2bf(v);
          }
        } else {
          float gt = gateg[grow];
          float* orow = out + (size_t)rowg[grow] * D_DIM;
#pragma unroll
          for (int nj = 0; nj < NFRAG; ++nj) {
            int col = n0 + wn * WN + nj * 16 + r16;
            float v = acc[mi][nj][r] + be[col];
            atomicAdd(&orow[col], gt * v);
          }
        }
      }
    }
  }
}

extern "C" void kernel_launch(void* const* d_in, const int* in_sizes, int n_in,
                              void* d_out, int out_size, void* d_ws, size_t ws_size,
                              hipStream_t stream) {
  const float* x   = (const float*)d_in[0];
  const float* eps = (const float*)d_in[1];
  const float* Wg  = (const float*)d_in[2];
  const float* bg  = (const float*)d_in[3];
  const float* Wn  = (const float*)d_in[4];
  const float* bn  = (const float*)d_in[5];
  const float* W1  = (const float*)d_in[6];
  const float* b1  = (const float*)d_in[7];
  const float* W2  = (const float*)d_in[8];
  const float* b2  = (const float*)d_in[9];
  float* out = (float*)d_out;

  const size_t nW = (size_t)E_NUM * D_DIM * H_DIM;
  ushort* W1T  = (ushort*)d_ws;         // [E][H][D-perm] bf16, 64MB
  ushort* W2T  = W1T + nW;              // [E][D][H-perm] bf16, 64MB
  ushort* xg   = W2T + nW;              // [GROWS][D-perm] bf16, 36MB
  ushort* hbuf = xg + (size_t)GROWS * D_DIM;  // [GROWS][H-perm] bf16, 144MB
  int*   tok   = (int*)(hbuf + (size_t)GROWS * H_DIM);
  float* gateL = (float*)(tok + E_NUM * T_TOK);
  int*   cnt   = (int*)(gateL + E_NUM * T_TOK);
  int*   goff  = cnt + 8;               // [9]
  float* gateg = (float*)(goff + 16);
  int*   rowg  = (int*)(gateg + GROWS);
  size_t need = (size_t)((char*)(rowg + GROWS) - (char*)d_ws);
  if (ws_size < need) return;

  hipMemsetAsync(cnt, 0, 8 * sizeof(int), stream);
  hipMemsetAsync(out, 0, (size_t)out_size * sizeof(float), stream);

  transpose_cvt_kernel<<<dim3(H_DIM / 64, D_DIM / 64, E_NUM), 256, 0, stream>>>(
      W1, W1T, D_DIM, H_DIM);
  transpose_cvt_kernel<<<dim3(D_DIM / 64, H_DIM / 64, E_NUM), 256, 0, stream>>>(
      W2, W2T, H_DIM, D_DIM);
  router_kernel<<<T_TOK / 4, 256, 0, stream>>>(x, eps, Wg, bg, Wn, bn, tok, gateL, cnt);
  plan_kernel<<<1, 64, 0, stream>>>(cnt, goff);
  compact_kernel<<<GROWS * 128 / 256, 256, 0, stream>>>(
      x, tok, gateL, cnt, goff, xg, gateg, rowg);
  moe_gemm_kernel<D_DIM, H_DIM, 256, true>
      <<<(GROWS / 256) * (H_DIM / 256), 512, 0, stream>>>(
          xg, W1T, b1, goff, cnt, gateg, rowg, hbuf, out);
  moe_gemm_kernel<H_DIM, D_DIM, 128, false>
      <<<(GROWS / 256) * (D_DIM / 128), 512, 0, stream>>>(
          hbuf, W2T, b2, goff, cnt, gateg, rowg, hbuf, out);
}